// Round 8
// baseline (8244.592 us; speedup 1.0000x reference)
//
#include <hip/hip_runtime.h>

typedef _Float16 h8 __attribute__((ext_vector_type(8)));
typedef float f4v __attribute__((ext_vector_type(4)));
typedef unsigned int u32;
typedef unsigned long long u64;
typedef u32 u32x4 __attribute__((ext_vector_type(4)));

#define SEQ 2048
#define HID 512
#define EMB 256
#define NV 32000
#define LOSCALE 2048.0f
#define INV_LOSCALE 4.8828125e-4f  // 2^-11

// ---- workspace layout (bytes) ----
#define WS_WHI 0u
#define WS_WLO (512u * 1024u)
#define WS_HG (1024u * 1024u)            // h: [2 buf][4 grp][2 plane][4096 u32] = 256 KB
#define WS_FLAGS (WS_HG + 256u * 1024u)  // 16 flags @ 128B stride (4 KB region)
#define WS_PROJ (WS_FLAGS + 4u * 1024u)
#define FLAG_STRIDE 32  // u32 units = 128 B

// ---------------------------------------------------------------------------
// K0: split W_hh (fp32 [k=512][j=512]) into f16 hi + f16 lo*2^11, stored in
// MFMA B-fragment stream order. Fragment c = jtg*16+kb (jtg in [0,32), 1KB
// each); lane l holds 8 f16 = W[kb*32+(l>>4)*8+e][jtg*16+(l&15)].
// ---------------------------------------------------------------------------
__global__ void wsplit_kernel(const float* __restrict__ Whh,
                              _Float16* __restrict__ Whi,
                              _Float16* __restrict__ Wlo) {
  int gid = blockIdx.x * 256 + threadIdx.x;  // 0..32767
  int l = gid & 63, c = gid >> 6;            // c in [0,512)
  int kb = c & 15, jtg = c >> 4;
  int j = jtg * 16 + (l & 15);
  int k0 = kb * 32 + (l >> 4) * 8;
  _Float16 hi[8], lo[8];
#pragma unroll
  for (int e = 0; e < 8; ++e) {
    float v = Whh[(k0 + e) * HID + j];
    _Float16 h = (_Float16)v;
    hi[e] = h;
    lo[e] = (_Float16)((v - (float)h) * LOSCALE);
  }
  *(h8*)(Whi + (size_t)gid * 8) = *(const h8*)hi;
  *(h8*)(Wlo + (size_t)gid * 8) = *(const h8*)lo;
}

// ---------------------------------------------------------------------------
// K1: projE[v][j] = sum_d E[v][d] * W_xh[d][j] + b_xh[j]  (32000 x 512)
// ---------------------------------------------------------------------------
template <bool PF32>
__global__ __launch_bounds__(256) void proj_kernel(const float* __restrict__ E,
                                                   const float* __restrict__ Wxh,
                                                   const float* __restrict__ bxh,
                                                   void* __restrict__ projE) {
  __shared__ float El[32 * EMB];
  const int t = threadIdx.x;
  const int v0 = blockIdx.x * 32;
  {
    const float4* src = (const float4*)(E + (size_t)v0 * EMB);
    float4* dst = (float4*)El;
#pragma unroll
    for (int i = 0; i < 8; ++i) dst[t + i * 256] = src[t + i * 256];
  }
  __syncthreads();
  const int c0 = (t & 63) * 8;
  const int rg = t >> 6;
  float acc[8][8];
#pragma unroll
  for (int r = 0; r < 8; ++r)
#pragma unroll
    for (int c = 0; c < 8; ++c) acc[r][c] = 0.f;

#pragma unroll 4
  for (int d = 0; d < EMB; ++d) {
    float wv[8];
    *(float4*)&wv[0] = *(const float4*)&Wxh[d * HID + c0];
    *(float4*)&wv[4] = *(const float4*)&Wxh[d * HID + c0 + 4];
#pragma unroll
    for (int r = 0; r < 8; ++r) {
      float ev = El[(rg * 8 + r) * EMB + d];
#pragma unroll
      for (int c = 0; c < 8; ++c) acc[r][c] = fmaf(ev, wv[c], acc[r][c]);
    }
  }
  float bv[8];
  *(float4*)&bv[0] = *(const float4*)&bxh[c0];
  *(float4*)&bv[4] = *(const float4*)&bxh[c0 + 4];
#pragma unroll
  for (int r = 0; r < 8; ++r) {
    int row = v0 + rg * 8 + r;
    if (PF32) {
      float o[8];
#pragma unroll
      for (int c = 0; c < 8; ++c) o[c] = acc[r][c] + bv[c];
      *(float4*)((float*)projE + (size_t)row * HID + c0) = *(const float4*)&o[0];
      *(float4*)((float*)projE + (size_t)row * HID + c0 + 4) = *(const float4*)&o[4];
    } else {
      _Float16 o[8];
#pragma unroll
      for (int c = 0; c < 8; ++c) o[c] = (_Float16)(acc[r][c] + bv[c]);
      *(h8*)((_Float16*)projE + (size_t)row * HID + c0) = *(const h8*)o;
    }
  }
}

// ---------------------------------------------------------------------------
// K2: zero h-exchange buffers (h0 = 0) and flags. 260 KB = 16640 float4.
// ---------------------------------------------------------------------------
__global__ void init_kernel(float4* __restrict__ p) {
  int gid = blockIdx.x * 256 + threadIdx.x;
  if (gid < 16640) p[gid] = (float4){0.f, 0.f, 0.f, 0.f};
}

// ---------------------------------------------------------------------------
// K3: persistent recurrence. 16 blocks = 4 batch-groups x 4 col-blocks,
// 512 threads (8 waves). Wave owns 16 output cols; W hi/lo slice pinned via
// inline-asm laundering (lives in unified VGPR/AGPR file, never re-streamed).
// h exchanged fence-free through packed-u32 global planes (agent-scope sc1
// write-through stores / loads); planes hold READY MFMA A-fragments.
// R8 changes vs R7:
//  * LDS double-buffered hs[2][8192]; epilogue dual-writes the block's OWN
//    quarter to next-step LDS, so staging covers only the 3 REMOTE quarters
//    (24 KB instead of 32 KB).
//  * Per-quarter gated staging: wave-pair q polls flag q only and stages
//    quarter q immediately -> 3 detect+load latencies overlap.
// Quarter q in LDS/global word space: plane p words [p*4096 + q*1024, +1024).
// ---------------------------------------------------------------------------
template <bool PF32>
__global__ __launch_bounds__(512, 2) void rnn_kernel(
    const int* __restrict__ X, const _Float16* __restrict__ Whi,
    const _Float16* __restrict__ Wlo, const void* __restrict__ projE,
    const float* __restrict__ bhh, u32* __restrict__ hX,
    u32* __restrict__ flags, float* __restrict__ out) {
  __shared__ u32 hs[2][8192];  // 64 KB: [buf][plane 2][kb 16][lane 64][m 4]
  const int tid = threadIdx.x;
  const int w = tid >> 6, lane = tid & 63;
  const int g = lane >> 4, li = lane & 15;
  const int grp = blockIdx.x >> 2, cb = blockIdx.x & 3;
  const int nb = grp * 16;
  const int jtg = cb * 8 + w;   // global j-tile 0..31
  const int j = jtg * 16 + li;  // global output col
  const int pairq = w >> 1;     // quarter this wave-pair stages
  const bool ownpair = (pairq == cb);
  const int p = (w & 1) * 64 + lane;  // 0..127 within pair

  // --- W slice into registers, laundered so it stays resident ---
  h8 Wh[16], Wl[16];
  {
    const char* wb = (const char*)Whi + ((size_t)jtg * 16 * 64 + lane) * 16;
    const char* wb2 = (const char*)Wlo + ((size_t)jtg * 16 * 64 + lane) * 16;
#pragma unroll
    for (int kb = 0; kb < 16; ++kb) {
      Wh[kb] = *(const h8*)(wb + (size_t)kb * 1024);
      Wl[kb] = *(const h8*)(wb2 + (size_t)kb * 1024);
    }
#pragma unroll
    for (int kb = 0; kb < 16; ++kb) {
      f4v th = __builtin_bit_cast(f4v, Wh[kb]);
      f4v tl = __builtin_bit_cast(f4v, Wl[kb]);
      asm volatile("" : "+v"(th), "+v"(tl));
      Wh[kb] = __builtin_bit_cast(h8, th);
      Wl[kb] = __builtin_bit_cast(h8, tl);
    }
  }
  const float bias = bhh[j];
  u32* fl = flags + grp * 4 * FLAG_STRIDE;

  // publish word index (u32, within this grp's 8192-u32 half)
  const int hi2 = ((jtg & 1) << 1) | (li >> 3);
  const int pub0 = (li & 1) * 4096 + (jtg >> 1) * 256 + (hi2 << 6) + g * 16 +
                   ((li & 7) >> 1);
  u32* const hgrp = hX + grp * 8192;
  const bool oddli = (li & 1) != 0;

  // zero hs[0] (h0 = 0); visible after first __syncthreads
#pragma unroll
  for (int i = 0; i < 16; ++i) hs[0][tid + i * 512] = 0u;

  const int* Xr[4];
#pragma unroll
  for (int i = 0; i < 4; ++i) Xr[i] = X + (size_t)(nb + g * 4 + i) * SEQ;

  for (int t = 0; t < SEQ; ++t) {
    // xp gather — independent of the protocol, issue first
    float pv[4];
#pragma unroll
    for (int i = 0; i < 4; ++i) {
      int tok = Xr[i][t];
      if (PF32)
        pv[i] = ((const float*)projE)[(size_t)tok * HID + j];
      else
        pv[i] = (float)((const _Float16*)projE)[(size_t)tok * HID + j];
    }

    // per-quarter gated stage: pair q polls flag q, then stages its 8 KB
    if (!ownpair) {
      if (t > 0 && lane == 0) {  // whole wave blocks until lane0 exits
        u32 spins = 0;
        while (__hip_atomic_load(fl + pairq * FLAG_STRIDE, __ATOMIC_RELAXED,
                                 __HIP_MEMORY_SCOPE_AGENT) < (u32)t) {
          if (++spins > 50000u) break;  // fail-fast instead of hang
        }
      }
      asm volatile("" ::: "memory");  // no load hoisting above the spin
      const u32* src = hgrp + (t & 1) * 32768;
      const int b0 = pairq * 1024 + p * 8;
      u64 v[2][4];
#pragma unroll
      for (int c = 0; c < 2; ++c) {
        const u32* s = src + b0 + c * 4096;
#pragma unroll
        for (int q = 0; q < 4; ++q)
          v[c][q] = __hip_atomic_load((const u64*)(s + q * 2),
                                      __ATOMIC_RELAXED,
                                      __HIP_MEMORY_SCOPE_AGENT);
      }
#pragma unroll
      for (int c = 0; c < 2; ++c) {
        u32x4 d0, d1;
        d0[0] = (u32)v[c][0]; d0[1] = (u32)(v[c][0] >> 32);
        d0[2] = (u32)v[c][1]; d0[3] = (u32)(v[c][1] >> 32);
        d1[0] = (u32)v[c][2]; d1[1] = (u32)(v[c][2] >> 32);
        d1[2] = (u32)v[c][3]; d1[3] = (u32)(v[c][3] >> 32);
        *(u32x4*)(&hs[t & 1][b0 + c * 4096]) = d0;
        *(u32x4*)(&hs[t & 1][b0 + c * 4096 + 4]) = d1;
      }
    }
    __syncthreads();

    // compute: fragments ready in LDS — 2 ds_read_b128 + 3 MFMA per kb
    f4v a1 = {0.f, 0.f, 0.f, 0.f};
    f4v c1 = {0.f, 0.f, 0.f, 0.f};
    f4v c2 = {0.f, 0.f, 0.f, 0.f};
    const u32* hb_hi = &hs[t & 1][lane * 4];
    const u32* hb_lo = hb_hi + 4096;
#pragma unroll
    for (int kb = 0; kb < 16; ++kb) {
      h8 ahc = *(const h8*)(hb_hi + kb * 256);
      h8 alc = *(const h8*)(hb_lo + kb * 256);
      a1 = __builtin_amdgcn_mfma_f32_16x16x32_f16(ahc, Wh[kb], a1, 0, 0, 0);
      c1 = __builtin_amdgcn_mfma_f32_16x16x32_f16(ahc, Wl[kb], c1, 0, 0, 0);
      c2 = __builtin_amdgcn_mfma_f32_16x16x32_f16(alc, Wh[kb], c2, 0, 0, 0);
    }

    // epilogue: tanh; pair lanes; publish to global AND own-quarter to LDS
    u32* const hn = hgrp + ((t + 1) & 1) * 32768;
    u32* const hsn = hs[(t + 1) & 1];
    const bool lastt = (t == SEQ - 1);
#pragma unroll
    for (int i = 0; i < 4; ++i) {
      float v = a1[i] + INV_LOSCALE * (c1[i] + c2[i]) + bias + pv[i];
      float e2 = __expf(2.0f * v);
      float th = 1.0f - 2.0f / (e2 + 1.0f);
      _Float16 hh = (_Float16)th;
      _Float16 hl = (_Float16)((th - (float)hh) * LOSCALE);
      u32 pk = (u32)__builtin_bit_cast(unsigned short, hh) |
               ((u32)__builtin_bit_cast(unsigned short, hl) << 16);
      u32 nbv = (u32)__shfl_xor((int)pk, 1, 64);
      // even li -> hi-plane word (self low half); odd li -> lo-plane word
      u32 word = oddli ? ((nbv >> 16) | (pk & 0xFFFF0000u))
                       : ((pk & 0xFFFFu) | (nbv << 16));
      __hip_atomic_store(hn + pub0 + i * 4, word, __ATOMIC_RELAXED,
                         __HIP_MEMORY_SCOPE_AGENT);
      hsn[pub0 + i * 4] = word;  // own quarter for next step, no restage
      if (lastt) out[(nb + g * 4 + i) * HID + j] = th;
    }
    __syncthreads();  // drains vmcnt per wave -> all sc1 stores visible
    if (tid == 0) {
      __hip_atomic_store(fl + cb * FLAG_STRIDE, (u32)(t + 1), __ATOMIC_RELAXED,
                         __HIP_MEMORY_SCOPE_AGENT);
    }
  }
}

// ---------------------------------------------------------------------------
extern "C" void kernel_launch(void* const* d_in, const int* in_sizes, int n_in,
                              void* d_out, int out_size, void* d_ws,
                              size_t ws_size, hipStream_t stream) {
  const int* X = (const int*)d_in[0];
  const float* E = (const float*)d_in[1];
  const float* Whh = (const float*)d_in[2];
  const float* bhh = (const float*)d_in[3];
  const float* Wxh = (const float*)d_in[4];
  const float* bxh = (const float*)d_in[5];
  float* out = (float*)d_out;

  char* ws = (char*)d_ws;
  _Float16* Whi = (_Float16*)(ws + WS_WHI);
  _Float16* Wlo = (_Float16*)(ws + WS_WLO);
  u32* hX = (u32*)(ws + WS_HG);
  u32* flags = (u32*)(ws + WS_FLAGS);
  void* projE = (void*)(ws + WS_PROJ);
  const bool pf32 = ws_size >= (size_t)WS_PROJ + (size_t)NV * HID * sizeof(float);

  wsplit_kernel<<<128, 256, 0, stream>>>(Whh, Whi, Wlo);
  init_kernel<<<65, 256, 0, stream>>>((float4*)(ws + WS_HG));
  if (pf32) {
    proj_kernel<true><<<NV / 32, 256, 0, stream>>>(E, Wxh, bxh, projE);
    rnn_kernel<true><<<16, 512, 0, stream>>>(X, Whi, Wlo, projE, bhh, hX, flags, out);
  } else {
    proj_kernel<false><<<NV / 32, 256, 0, stream>>>(E, Wxh, bxh, projE);
    rnn_kernel<false><<<16, 512, 0, stream>>>(X, Whi, Wlo, projE, bhh, hX, flags, out);
  }
}

// Round 10
// 8078.152 us; speedup vs baseline: 1.0206x; 1.0206x over previous
//
#include <hip/hip_runtime.h>

typedef _Float16 h8 __attribute__((ext_vector_type(8)));
typedef float f4v __attribute__((ext_vector_type(4)));
typedef unsigned int u32;
typedef unsigned long long u64;
typedef u32 u32x4 __attribute__((ext_vector_type(4)));

#define SEQ 2048
#define HID 512
#define EMB 256
#define NV 32000
#define LOSCALE 2048.0f
#define INV_LOSCALE 4.8828125e-4f  // 2^-11

// ---- workspace layout (bytes) ----
#define WS_WHI 0u
#define WS_WLO (512u * 1024u)
#define WS_HG (1024u * 1024u)            // h: [2 buf][4 grp][2 plane][4096 u32] = 256 KB
#define WS_FLAGS (WS_HG + 256u * 1024u)  // 16 flags @ 128B stride (4 KB region)
#define WS_PROJ (WS_FLAGS + 4u * 1024u)
#define FLAG_STRIDE 32  // u32 units = 128 B

// sc1 = agent-scope cache op (bypass non-coherent per-XCD L2, served at the
// device coherence point). Same encoding the __hip_atomic_* AGENT intrinsics
// emit — R7 proved the protocol with those; these helpers only batch issue.
static __device__ __forceinline__ u32 ld_sc1(const u32* p) {
  u32 r;
  asm volatile("global_load_dword %0, %1, off sc1\n\ts_waitcnt vmcnt(0)"
               : "=v"(r) : "v"(p) : "memory");
  return r;
}
static __device__ __forceinline__ void st_sc1(u32* p, u32 v) {
  asm volatile("global_store_dword %0, %1, off sc1" ::"v"(p), "v"(v)
               : "memory");
}

// ---------------------------------------------------------------------------
// K0: split W_hh (fp32 [k=512][j=512]) into f16 hi + f16 lo*2^11, stored in
// MFMA B-fragment stream order (verified R3-R7).
// ---------------------------------------------------------------------------
__global__ void wsplit_kernel(const float* __restrict__ Whh,
                              _Float16* __restrict__ Whi,
                              _Float16* __restrict__ Wlo) {
  int gid = blockIdx.x * 256 + threadIdx.x;  // 0..32767
  int l = gid & 63, c = gid >> 6;            // c in [0,512)
  int kb = c & 15, jtg = c >> 4;
  int j = jtg * 16 + (l & 15);
  int k0 = kb * 32 + (l >> 4) * 8;
  _Float16 hi[8], lo[8];
#pragma unroll
  for (int e = 0; e < 8; ++e) {
    float v = Whh[(k0 + e) * HID + j];
    _Float16 h = (_Float16)v;
    hi[e] = h;
    lo[e] = (_Float16)((v - (float)h) * LOSCALE);
  }
  *(h8*)(Whi + (size_t)gid * 8) = *(const h8*)hi;
  *(h8*)(Wlo + (size_t)gid * 8) = *(const h8*)lo;
}

// ---------------------------------------------------------------------------
// K1: projE[v][j] = sum_d E[v][d] * W_xh[d][j] + b_xh[j]  (32000 x 512)
// ---------------------------------------------------------------------------
template <bool PF32>
__global__ __launch_bounds__(256) void proj_kernel(const float* __restrict__ E,
                                                   const float* __restrict__ Wxh,
                                                   const float* __restrict__ bxh,
                                                   void* __restrict__ projE) {
  __shared__ float El[32 * EMB];
  const int t = threadIdx.x;
  const int v0 = blockIdx.x * 32;
  {
    const float4* src = (const float4*)(E + (size_t)v0 * EMB);
    float4* dst = (float4*)El;
#pragma unroll
    for (int i = 0; i < 8; ++i) dst[t + i * 256] = src[t + i * 256];
  }
  __syncthreads();
  const int c0 = (t & 63) * 8;
  const int rg = t >> 6;
  float acc[8][8];
#pragma unroll
  for (int r = 0; r < 8; ++r)
#pragma unroll
    for (int c = 0; c < 8; ++c) acc[r][c] = 0.f;

#pragma unroll 4
  for (int d = 0; d < EMB; ++d) {
    float wv[8];
    *(float4*)&wv[0] = *(const float4*)&Wxh[d * HID + c0];
    *(float4*)&wv[4] = *(const float4*)&Wxh[d * HID + c0 + 4];
#pragma unroll
    for (int r = 0; r < 8; ++r) {
      float ev = El[(rg * 8 + r) * EMB + d];
#pragma unroll
      for (int c = 0; c < 8; ++c) acc[r][c] = fmaf(ev, wv[c], acc[r][c]);
    }
  }
  float bv[8];
  *(float4*)&bv[0] = *(const float4*)&bxh[c0];
  *(float4*)&bv[4] = *(const float4*)&bxh[c0 + 4];
#pragma unroll
  for (int r = 0; r < 8; ++r) {
    int row = v0 + rg * 8 + r;
    if (PF32) {
      float o[8];
#pragma unroll
      for (int c = 0; c < 8; ++c) o[c] = acc[r][c] + bv[c];
      *(float4*)((float*)projE + (size_t)row * HID + c0) = *(const float4*)&o[0];
      *(float4*)((float*)projE + (size_t)row * HID + c0 + 4) = *(const float4*)&o[4];
    } else {
      _Float16 o[8];
#pragma unroll
      for (int c = 0; c < 8; ++c) o[c] = (_Float16)(acc[r][c] + bv[c]);
      *(h8*)((_Float16*)projE + (size_t)row * HID + c0) = *(const h8*)o;
    }
  }
}

// ---------------------------------------------------------------------------
// K2: zero h-exchange buffers (h0 = 0) and flags. 260 KB = 16640 float4.
// ---------------------------------------------------------------------------
__global__ void init_kernel(float4* __restrict__ p) {
  int gid = blockIdx.x * 256 + threadIdx.x;
  if (gid < 16640) p[gid] = (float4){0.f, 0.f, 0.f, 0.f};
}

// ---------------------------------------------------------------------------
// K3: persistent recurrence. IDENTICAL protocol/layout to the passing R7
// kernel (16 blocks = 4 batch-groups x 4 col-blocks, 512 threads, W pinned
// in regs via laundering, fence-free sc1 exchange, monotonic flags).
// Single change: exchange ops are inline-asm sc1 with BATCHED issue —
// staging = 4 x global_load_dwordx4 in one asm block + ONE vmcnt(0),
// instead of per-atomic-load drains (the R7 serialization).
// ---------------------------------------------------------------------------
template <bool PF32>
__global__ __launch_bounds__(512, 2) void rnn_kernel(
    const int* __restrict__ X, const _Float16* __restrict__ Whi,
    const _Float16* __restrict__ Wlo, const void* __restrict__ projE,
    const float* __restrict__ bhh, u32* __restrict__ hX,
    u32* __restrict__ flags, float* __restrict__ out) {
  __shared__ u32 hs[8192];  // 32 KB staged h: [plane 2][kb 16][lane 64][m 4]
  const int tid = threadIdx.x;
  const int w = tid >> 6, lane = tid & 63;
  const int g = lane >> 4, li = lane & 15;
  const int grp = blockIdx.x >> 2, cb = blockIdx.x & 3;
  const int nb = grp * 16;
  const int jtg = cb * 8 + w;   // global j-tile 0..31
  const int j = jtg * 16 + li;  // global output col

  // --- W slice into registers, laundered so it stays resident ---
  h8 Wh[16], Wl[16];
  {
    const char* wb = (const char*)Whi + ((size_t)jtg * 16 * 64 + lane) * 16;
    const char* wb2 = (const char*)Wlo + ((size_t)jtg * 16 * 64 + lane) * 16;
#pragma unroll
    for (int kb = 0; kb < 16; ++kb) {
      Wh[kb] = *(const h8*)(wb + (size_t)kb * 1024);
      Wl[kb] = *(const h8*)(wb2 + (size_t)kb * 1024);
    }
#pragma unroll
    for (int kb = 0; kb < 16; ++kb) {
      f4v th = __builtin_bit_cast(f4v, Wh[kb]);
      f4v tl = __builtin_bit_cast(f4v, Wl[kb]);
      asm volatile("" : "+v"(th), "+v"(tl));
      Wh[kb] = __builtin_bit_cast(h8, th);
      Wl[kb] = __builtin_bit_cast(h8, tl);
    }
  }
  const float bias = bhh[j];
  u32* fl = flags + grp * 4 * FLAG_STRIDE;
  u32* flself = fl + cb * FLAG_STRIDE;

  // publish word index (u32, within this grp's 8192-u32 half) — R7-verified
  const int hi2 = ((jtg & 1) << 1) | (li >> 3);
  const int pub0 = (li & 1) * 4096 + (jtg >> 1) * 256 + (hi2 << 6) + g * 16 +
                   ((li & 7) >> 1);
  u32* const hgrp = hX + grp * 8192;
  const bool oddli = (li & 1) != 0;

  const int* Xr[4];
#pragma unroll
  for (int i = 0; i < 4; ++i) Xr[i] = X + (size_t)(nb + g * 4 + i) * SEQ;

  for (int t = 0; t < SEQ; ++t) {
    // xp gather — plain cached loads, issued before the spin; latency hides
    // under spin+stage (pv first consumed in the epilogue)
    float pv[4];
#pragma unroll
    for (int i = 0; i < 4; ++i) {
      int tok = Xr[i][t];
      if (PF32)
        pv[i] = ((const float*)projE)[(size_t)tok * HID + j];
      else
        pv[i] = (float)((const _Float16*)projE)[(size_t)tok * HID + j];
    }

    // lane-parallel spin: lane b (<4) of EVERY wave polls group flag b (sc1)
    if (t > 0 && lane < 4) {
      const u32* fp = fl + lane * FLAG_STRIDE;
      u32 spins = 0;
      while (ld_sc1(fp) < (u32)t) {
        if (++spins > 300000u) break;  // fail-fast instead of hang
      }
    }

    // cooperative stage: 32 KB group-h -> LDS; 4 sc1 dwordx4 loads batched
    // in ONE asm block with a single vmcnt(0) (the R10 fix)
    {
      const u32* src = hgrp + (t & 1) * 32768 + tid * 4;
      u32x4 a0, a1, a2, a3;
      asm volatile(
          "global_load_dwordx4 %0, %4, off sc1\n\t"
          "global_load_dwordx4 %1, %5, off sc1\n\t"
          "global_load_dwordx4 %2, %6, off sc1\n\t"
          "global_load_dwordx4 %3, %7, off sc1\n\t"
          "s_waitcnt vmcnt(0)"
          : "=&v"(a0), "=&v"(a1), "=&v"(a2), "=&v"(a3)
          : "v"(src), "v"(src + 2048), "v"(src + 4096), "v"(src + 6144)
          : "memory");
      *(u32x4*)(hs + tid * 4) = a0;
      *(u32x4*)(hs + tid * 4 + 2048) = a1;
      *(u32x4*)(hs + tid * 4 + 4096) = a2;
      *(u32x4*)(hs + tid * 4 + 6144) = a3;
    }
    __syncthreads();

    // compute: fragments ready in LDS — 2 ds_read_b128 + 3 MFMA per kb
    f4v a1 = {0.f, 0.f, 0.f, 0.f};
    f4v c1 = {0.f, 0.f, 0.f, 0.f};
    f4v c2 = {0.f, 0.f, 0.f, 0.f};
    const u32* hb_hi = hs + lane * 4;
    const u32* hb_lo = hb_hi + 4096;
#pragma unroll
    for (int kb = 0; kb < 16; ++kb) {
      h8 ahc = *(const h8*)(hb_hi + kb * 256);
      h8 alc = *(const h8*)(hb_lo + kb * 256);
      a1 = __builtin_amdgcn_mfma_f32_16x16x32_f16(ahc, Wh[kb], a1, 0, 0, 0);
      c1 = __builtin_amdgcn_mfma_f32_16x16x32_f16(ahc, Wl[kb], c1, 0, 0, 0);
      c2 = __builtin_amdgcn_mfma_f32_16x16x32_f16(alc, Wh[kb], c2, 0, 0, 0);
    }

    // epilogue: tanh; pair lanes; publish plane-separated words (sc1)
    u32* const hn = hgrp + ((t + 1) & 1) * 32768;
    const bool lastt = (t == SEQ - 1);
#pragma unroll
    for (int i = 0; i < 4; ++i) {
      float v = a1[i] + INV_LOSCALE * (c1[i] + c2[i]) + bias + pv[i];
      float e2 = __expf(2.0f * v);
      float th = 1.0f - 2.0f / (e2 + 1.0f);
      _Float16 hh = (_Float16)th;
      _Float16 hl = (_Float16)((th - (float)hh) * LOSCALE);
      u32 pk = (u32)__builtin_bit_cast(unsigned short, hh) |
               ((u32)__builtin_bit_cast(unsigned short, hl) << 16);
      u32 nbv = (u32)__shfl_xor((int)pk, 1, 64);
      u32 word = oddli ? ((nbv >> 16) | (pk & 0xFFFF0000u))
                       : ((pk & 0xFFFFu) | (nbv << 16));
      st_sc1(hn + pub0 + i * 4, word);
      if (lastt) out[(nb + g * 4 + i) * HID + j] = th;
    }
    asm volatile("s_waitcnt vmcnt(0)" ::: "memory");  // publishes committed
    __syncthreads();  // all waves drained before the flag
    if (tid == 0) st_sc1(flself, (u32)(t + 1));
  }
}

// ---------------------------------------------------------------------------
extern "C" void kernel_launch(void* const* d_in, const int* in_sizes, int n_in,
                              void* d_out, int out_size, void* d_ws,
                              size_t ws_size, hipStream_t stream) {
  const int* X = (const int*)d_in[0];
  const float* E = (const float*)d_in[1];
  const float* Whh = (const float*)d_in[2];
  const float* bhh = (const float*)d_in[3];
  const float* Wxh = (const float*)d_in[4];
  const float* bxh = (const float*)d_in[5];
  float* out = (float*)d_out;

  char* ws = (char*)d_ws;
  _Float16* Whi = (_Float16*)(ws + WS_WHI);
  _Float16* Wlo = (_Float16*)(ws + WS_WLO);
  u32* hX = (u32*)(ws + WS_HG);
  u32* flags = (u32*)(ws + WS_FLAGS);
  void* projE = (void*)(ws + WS_PROJ);
  const bool pf32 = ws_size >= (size_t)WS_PROJ + (size_t)NV * HID * sizeof(float);

  wsplit_kernel<<<128, 256, 0, stream>>>(Whh, Whi, Wlo);
  init_kernel<<<65, 256, 0, stream>>>((float4*)(ws + WS_HG));
  if (pf32) {
    proj_kernel<true><<<NV / 32, 256, 0, stream>>>(E, Wxh, bxh, projE);
    rnn_kernel<true><<<16, 512, 0, stream>>>(X, Whi, Wlo, projE, bhh, hX, flags, out);
  } else {
    proj_kernel<false><<<NV / 32, 256, 0, stream>>>(E, Wxh, bxh, projE);
    rnn_kernel<false><<<16, 512, 0, stream>>>(X, Whi, Wlo, projE, bhh, hX, flags, out);
  }
}

// Round 12
// 6453.040 us; speedup vs baseline: 1.2776x; 1.2518x over previous
//
#include <hip/hip_runtime.h>

typedef _Float16 h8 __attribute__((ext_vector_type(8)));
typedef float f4v __attribute__((ext_vector_type(4)));
typedef unsigned int u32;
typedef unsigned short u16;
typedef unsigned long long u64;
typedef u32 u32x4 __attribute__((ext_vector_type(4)));

#define SEQ 2048
#define HID 512
#define EMB 256
#define NV 32000
#define LOSCALE 2048.0f
#define INV_LOSCALE 4.8828125e-4f  // 2^-11

// ---- workspace layout (bytes) ----
#define WS_WHI 0u
#define WS_WLO (512u * 1024u)
#define WS_HG (1024u * 1024u)            // h: [2 buf][4 grp][2 plane][4096 u32] = 256 KB
#define WS_FLAGS (WS_HG + 256u * 1024u)  // legacy flag region (unused, keeps WS_PROJ fixed)
#define WS_PROJ (WS_FLAGS + 4u * 1024u)

// ---------------------------------------------------------------------------
// K0: split W_hh (fp32 [k=512][j=512]) into f16 hi + f16 lo*2^11, stored in
// MFMA B-fragment stream order (verified R3-R7).
// ---------------------------------------------------------------------------
__global__ void wsplit_kernel(const float* __restrict__ Whh,
                              _Float16* __restrict__ Whi,
                              _Float16* __restrict__ Wlo) {
  int gid = blockIdx.x * 256 + threadIdx.x;  // 0..32767
  int l = gid & 63, c = gid >> 6;            // c in [0,512)
  int kb = c & 15, jtg = c >> 4;
  int j = jtg * 16 + (l & 15);
  int k0 = kb * 32 + (l >> 4) * 8;
  _Float16 hi[8], lo[8];
#pragma unroll
  for (int e = 0; e < 8; ++e) {
    float v = Whh[(k0 + e) * HID + j];
    _Float16 h = (_Float16)v;
    hi[e] = h;
    lo[e] = (_Float16)((v - (float)h) * LOSCALE);
  }
  *(h8*)(Whi + (size_t)gid * 8) = *(const h8*)hi;
  *(h8*)(Wlo + (size_t)gid * 8) = *(const h8*)lo;
}

// ---------------------------------------------------------------------------
// K1: projE[v][j] = sum_d E[v][d] * W_xh[d][j] + b_xh[j]  (32000 x 512)
// ---------------------------------------------------------------------------
template <bool PF32>
__global__ __launch_bounds__(256) void proj_kernel(const float* __restrict__ E,
                                                   const float* __restrict__ Wxh,
                                                   const float* __restrict__ bxh,
                                                   void* __restrict__ projE) {
  __shared__ float El[32 * EMB];
  const int t = threadIdx.x;
  const int v0 = blockIdx.x * 32;
  {
    const float4* src = (const float4*)(E + (size_t)v0 * EMB);
    float4* dst = (float4*)El;
#pragma unroll
    for (int i = 0; i < 8; ++i) dst[t + i * 256] = src[t + i * 256];
  }
  __syncthreads();
  const int c0 = (t & 63) * 8;
  const int rg = t >> 6;
  float acc[8][8];
#pragma unroll
  for (int r = 0; r < 8; ++r)
#pragma unroll
    for (int c = 0; c < 8; ++c) acc[r][c] = 0.f;

#pragma unroll 4
  for (int d = 0; d < EMB; ++d) {
    float wv[8];
    *(float4*)&wv[0] = *(const float4*)&Wxh[d * HID + c0];
    *(float4*)&wv[4] = *(const float4*)&Wxh[d * HID + c0 + 4];
#pragma unroll
    for (int r = 0; r < 8; ++r) {
      float ev = El[(rg * 8 + r) * EMB + d];
#pragma unroll
      for (int c = 0; c < 8; ++c) acc[r][c] = fmaf(ev, wv[c], acc[r][c]);
    }
  }
  float bv[8];
  *(float4*)&bv[0] = *(const float4*)&bxh[c0];
  *(float4*)&bv[4] = *(const float4*)&bxh[c0 + 4];
#pragma unroll
  for (int r = 0; r < 8; ++r) {
    int row = v0 + rg * 8 + r;
    if (PF32) {
      float o[8];
#pragma unroll
      for (int c = 0; c < 8; ++c) o[c] = acc[r][c] + bv[c];
      *(float4*)((float*)projE + (size_t)row * HID + c0) = *(const float4*)&o[0];
      *(float4*)((float*)projE + (size_t)row * HID + c0 + 4) = *(const float4*)&o[4];
    } else {
      _Float16 o[8];
#pragma unroll
      for (int c = 0; c < 8; ++c) o[c] = (_Float16)(acc[r][c] + bv[c]);
      *(h8*)((_Float16*)projE + (size_t)row * HID + c0) = *(const h8*)o;
    }
  }
}

// ---------------------------------------------------------------------------
// K2: init exchange state. Buffer 0 (float4 idx [0,8192)) = zeros: this IS
// h0 with epoch bit 0 (valid at t=0,1... no — valid at t=0 only, see below).
// Buffer 1 (idx [8192,16384)) = per-u32 0x00000001: bit0=1 marks INVALID for
// t=1's expected epoch 0, closing the R11 init/h1 epoch collision (published
// h1 carries epoch 0 and must be distinguishable from init state). Flags
// region (idx [16384,16640)) zeroed (legacy, unused).
// ---------------------------------------------------------------------------
__global__ void init_kernel(float4* __restrict__ p) {
  int gid = blockIdx.x * 256 + threadIdx.x;
  if (gid < 16640) {
    float4 z = {0.f, 0.f, 0.f, 0.f};
    if (gid >= 8192 && gid < 16384) {
      float one = __uint_as_float(1u);  // bit0 set in every u32 word
      z = (float4){one, one, one, one};
    }
    p[gid] = z;
  }
}

// ---------------------------------------------------------------------------
// K3: persistent recurrence. Structure/layout byte-identical to the passing
// R7 kernel (16 blocks = 4 grp x 4 col-blocks, 512 thr, W laundered into the
// unified reg file, sc1 packed-u32 exchange). ONE mechanism changed vs R7:
// FLAGLESS EPOCH-BIT SYNC. Every published u32 word carries epoch
// e=(step>>1)&1 in bit0 (f16-LSB of the even lane's hi/lo half; lo is
// recomputed AFTER forcing hi so h == hi + lo/2048 still holds to ~2^-20).
// The reader's staging loads double as the sync: reload until all 16 words
// show the expected epoch. Deletes 3 serial protocol legs per step
// (vmcnt-drain, flag store+land, detect-then-stage).
// Safety induction (skew <= 2): to accept buffer contents as h_{t+4} when
// they are h_t requires a 4-step skew; but passing validation at t+3 proves
// every block published h_{t+3}, i.e. finished step t+2 — contradiction.
// Init collision at t=1 fixed in K2 (buffer 1 pre-marked epoch-1-invalid).
// ---------------------------------------------------------------------------
template <bool PF32>
__global__ __launch_bounds__(512, 2) void rnn_kernel(
    const int* __restrict__ X, const _Float16* __restrict__ Whi,
    const _Float16* __restrict__ Wlo, const void* __restrict__ projE,
    const float* __restrict__ bhh, u32* __restrict__ hX,
    float* __restrict__ out) {
  __shared__ u32 hs[8192];  // 32 KB staged h: [plane 2][kb 16][lane 64][m 4]
  const int tid = threadIdx.x;
  const int w = tid >> 6, lane = tid & 63;
  const int g = lane >> 4, li = lane & 15;
  const int grp = blockIdx.x >> 2, cb = blockIdx.x & 3;
  const int nb = grp * 16;
  const int jtg = cb * 8 + w;   // global j-tile 0..31
  const int j = jtg * 16 + li;  // global output col

  // --- W slice into registers, laundered so it stays resident ---
  h8 Wh[16], Wl[16];
  {
    const char* wb = (const char*)Whi + ((size_t)jtg * 16 * 64 + lane) * 16;
    const char* wb2 = (const char*)Wlo + ((size_t)jtg * 16 * 64 + lane) * 16;
#pragma unroll
    for (int kb = 0; kb < 16; ++kb) {
      Wh[kb] = *(const h8*)(wb + (size_t)kb * 1024);
      Wl[kb] = *(const h8*)(wb2 + (size_t)kb * 1024);
    }
#pragma unroll
    for (int kb = 0; kb < 16; ++kb) {
      f4v th = __builtin_bit_cast(f4v, Wh[kb]);
      f4v tl = __builtin_bit_cast(f4v, Wl[kb]);
      asm volatile("" : "+v"(th), "+v"(tl));
      Wh[kb] = __builtin_bit_cast(h8, th);
      Wl[kb] = __builtin_bit_cast(h8, tl);
    }
  }
  const float bias = bhh[j];

  // publish word index (u32, within this grp's 8192-u32 half) — R7-verified
  const int hi2 = ((jtg & 1) << 1) | (li >> 3);
  const int pub0 = (li & 1) * 4096 + (jtg >> 1) * 256 + (hi2 << 6) + g * 16 +
                   ((li & 7) >> 1);
  u32* const hgrp = hX + grp * 8192;
  const bool oddli = (li & 1) != 0;

  const int* Xr[4];
#pragma unroll
  for (int i = 0; i < 4; ++i) Xr[i] = X + (size_t)(nb + g * 4 + i) * SEQ;

  for (int t = 0; t < SEQ; ++t) {
    // xp gather — plain cached loads; latency hides under validate+stage
    float pv[4];
#pragma unroll
    for (int i = 0; i < 4; ++i) {
      int tok = Xr[i][t];
      if (PF32)
        pv[i] = ((const float*)projE)[(size_t)tok * HID + j];
      else
        pv[i] = (float)((const _Float16*)projE)[(size_t)tok * HID + j];
    }

    // validate+stage: reload this thread's 16 words until every word shows
    // the expected epoch bit (the loads ARE the synchronization)
    const u32 e = (u32)(t >> 1) & 1u;
    const u32* src = hgrp + (t & 1) * 32768 + tid * 4;
    u64 v[4][2];
    {
      int tries = 0;
      while (true) {
#pragma unroll
        for (int q = 0; q < 4; ++q) {
          v[q][0] = __hip_atomic_load((const u64*)(src + q * 2048),
                                      __ATOMIC_RELAXED,
                                      __HIP_MEMORY_SCOPE_AGENT);
          v[q][1] = __hip_atomic_load((const u64*)(src + q * 2048 + 2),
                                      __ATOMIC_RELAXED,
                                      __HIP_MEMORY_SCOPE_AGENT);
        }
        u64 orr = (v[0][0] | v[0][1]) | (v[1][0] | v[1][1]) |
                  (v[2][0] | v[2][1]) | (v[3][0] | v[3][1]);
        u64 andd = (v[0][0] & v[0][1]) & (v[1][0] & v[1][1]) &
                   (v[2][0] & v[2][1]) & (v[3][0] & v[3][1]);
        bool ok;
        if (e)
          ok = ((andd & 1ull) != 0) && (((andd >> 32) & 1ull) != 0);
        else
          ok = ((orr & 1ull) == 0) && (((orr >> 32) & 1ull) == 0);
        if (__all(ok) || ++tries > 200000) break;  // cap: fail-fast, no hang
      }
    }
#pragma unroll
    for (int q = 0; q < 4; ++q) {
      u32x4 d;
      d[0] = (u32)v[q][0]; d[1] = (u32)(v[q][0] >> 32);
      d[2] = (u32)v[q][1]; d[3] = (u32)(v[q][1] >> 32);
      *(u32x4*)(hs + tid * 4 + q * 2048) = d;
    }
    __syncthreads();

    // compute: fragments ready in LDS — 2 ds_read_b128 + 3 MFMA per kb
    f4v a1 = {0.f, 0.f, 0.f, 0.f};
    f4v c1 = {0.f, 0.f, 0.f, 0.f};
    f4v c2 = {0.f, 0.f, 0.f, 0.f};
    const u32* hb_hi = hs + lane * 4;
    const u32* hb_lo = hb_hi + 4096;
#pragma unroll
    for (int kb = 0; kb < 16; ++kb) {
      h8 ahc = *(const h8*)(hb_hi + kb * 256);
      h8 alc = *(const h8*)(hb_lo + kb * 256);
      a1 = __builtin_amdgcn_mfma_f32_16x16x32_f16(ahc, Wh[kb], a1, 0, 0, 0);
      c1 = __builtin_amdgcn_mfma_f32_16x16x32_f16(ahc, Wl[kb], c1, 0, 0, 0);
      c2 = __builtin_amdgcn_mfma_f32_16x16x32_f16(alc, Wh[kb], c2, 0, 0, 0);
    }

    // epilogue: tanh; force epoch bit (even li halves); pair; publish (sc1,
    // fire-and-forget — readers' validation loop absorbs landing latency)
    u32* const hn = hgrp + ((t + 1) & 1) * 32768;
    const u32 ep = (u32)((t + 1) >> 1) & 1u;
    const bool lastt = (t == SEQ - 1);
#pragma unroll
    for (int i = 0; i < 4; ++i) {
      float vfull = a1[i] + INV_LOSCALE * (c1[i] + c2[i]) + bias + pv[i];
      float e2 = __expf(2.0f * vfull);
      float th = 1.0f - 2.0f / (e2 + 1.0f);
      _Float16 hh = (_Float16)th;
      u16 h16 = __builtin_bit_cast(u16, hh);
      if (!oddli) h16 = (u16)((h16 & 0xFFFEu) | ep);
      hh = __builtin_bit_cast(_Float16, h16);  // recompute lo vs FORCED hi
      _Float16 hl = (_Float16)((th - (float)hh) * LOSCALE);
      u16 l16 = __builtin_bit_cast(u16, hl);
      if (!oddli) l16 = (u16)((l16 & 0xFFFEu) | ep);
      u32 pk = (u32)h16 | ((u32)l16 << 16);
      u32 nbv = (u32)__shfl_xor((int)pk, 1, 64);
      // even li -> hi-plane word [self.hi | nb.hi]; odd -> lo-plane word
      // [nb.lo | self.lo]; bit0 of both = even lane's forced LSB
      u32 word = oddli ? ((nbv >> 16) | (pk & 0xFFFF0000u))
                       : ((pk & 0xFFFFu) | (nbv << 16));
      __hip_atomic_store(hn + pub0 + i * 4, word, __ATOMIC_RELAXED,
                         __HIP_MEMORY_SCOPE_AGENT);
      if (lastt) out[(nb + g * 4 + i) * HID + j] = th;
    }
    __syncthreads();  // protect hs before next iteration's overwrite
  }
}

// ---------------------------------------------------------------------------
extern "C" void kernel_launch(void* const* d_in, const int* in_sizes, int n_in,
                              void* d_out, int out_size, void* d_ws,
                              size_t ws_size, hipStream_t stream) {
  const int* X = (const int*)d_in[0];
  const float* E = (const float*)d_in[1];
  const float* Whh = (const float*)d_in[2];
  const float* bhh = (const float*)d_in[3];
  const float* Wxh = (const float*)d_in[4];
  const float* bxh = (const float*)d_in[5];
  float* out = (float*)d_out;

  char* ws = (char*)d_ws;
  _Float16* Whi = (_Float16*)(ws + WS_WHI);
  _Float16* Wlo = (_Float16*)(ws + WS_WLO);
  u32* hX = (u32*)(ws + WS_HG);
  void* projE = (void*)(ws + WS_PROJ);
  const bool pf32 = ws_size >= (size_t)WS_PROJ + (size_t)NV * HID * sizeof(float);

  wsplit_kernel<<<128, 256, 0, stream>>>(Whh, Whi, Wlo);
  init_kernel<<<65, 256, 0, stream>>>((float4*)(ws + WS_HG));
  if (pf32) {
    proj_kernel<true><<<NV / 32, 256, 0, stream>>>(E, Wxh, bxh, projE);
    rnn_kernel<true><<<16, 512, 0, stream>>>(X, Whi, Wlo, projE, bhh, hX, out);
  } else {
    proj_kernel<false><<<NV / 32, 256, 0, stream>>>(E, Wxh, bxh, projE);
    rnn_kernel<false><<<16, 512, 0, stream>>>(X, Whi, Wlo, projE, bhh, hX, out);
  }
}

// Round 13
// 6058.620 us; speedup vs baseline: 1.3608x; 1.0651x over previous
//
#include <hip/hip_runtime.h>

typedef _Float16 h8 __attribute__((ext_vector_type(8)));
typedef float f4v __attribute__((ext_vector_type(4)));
typedef unsigned int u32;
typedef unsigned short u16;
typedef unsigned long long u64;
typedef u32 u32x4 __attribute__((ext_vector_type(4)));

#define SEQ 2048
#define HID 512
#define EMB 256
#define NV 32000
#define LOSCALE 2048.0f
#define INV_LOSCALE 4.8828125e-4f  // 2^-11

// ---- workspace layout (bytes) ----
#define WS_WHI 0u
#define WS_WLO (512u * 1024u)
#define WS_HG (1024u * 1024u)            // h: [2 buf][4 grp][2 plane][4096 u32] = 256 KB
#define WS_CLAIM (WS_HG + 256u * 1024u)  // claim/handshake region (4 KB, zeroed)
#define WS_PROJ (WS_CLAIM + 4u * 1024u)

// sc0 = L1-bypass, served by the (per-XCD) L2 — valid coherence point ONLY
// for same-XCD blocks; usage gated by the runtime handshake below.
static __device__ __forceinline__ u32 ld_sc0_u32(const u32* p) {
  u32 r;
  asm volatile("global_load_dword %0, %1, off sc0\n\ts_waitcnt vmcnt(0)"
               : "=v"(r) : "v"(p) : "memory");
  return r;
}
static __device__ __forceinline__ void st_sc0_u32(u32* p, u32 v) {
  asm volatile("global_store_dword %0, %1, off sc0" ::"v"(p), "v"(v)
               : "memory");
}

// batched staging loads: 8 x 8B in ONE asm block + single vmcnt (SC0 path);
// SC1 path = R12's proven intrinsic loads (compiler batches + waits itself).
template <bool SC0>
static __device__ __forceinline__ void load8(const u32* src, u64 v[4][2]) {
  if constexpr (SC0) {
    asm volatile(
        "global_load_dwordx2 %0, %8, off sc0\n\t"
        "global_load_dwordx2 %1, %9, off sc0\n\t"
        "global_load_dwordx2 %2, %10, off sc0\n\t"
        "global_load_dwordx2 %3, %11, off sc0\n\t"
        "global_load_dwordx2 %4, %12, off sc0\n\t"
        "global_load_dwordx2 %5, %13, off sc0\n\t"
        "global_load_dwordx2 %6, %14, off sc0\n\t"
        "global_load_dwordx2 %7, %15, off sc0\n\t"
        "s_waitcnt vmcnt(0)"
        : "=&v"(v[0][0]), "=&v"(v[0][1]), "=&v"(v[1][0]), "=&v"(v[1][1]),
          "=&v"(v[2][0]), "=&v"(v[2][1]), "=&v"(v[3][0]), "=&v"(v[3][1])
        : "v"((const u64*)(src)), "v"((const u64*)(src + 2)),
          "v"((const u64*)(src + 2048)), "v"((const u64*)(src + 2050)),
          "v"((const u64*)(src + 4096)), "v"((const u64*)(src + 4098)),
          "v"((const u64*)(src + 6144)), "v"((const u64*)(src + 6146))
        : "memory");
  } else {
#pragma unroll
    for (int q = 0; q < 4; ++q) {
      v[q][0] = __hip_atomic_load((const u64*)(src + q * 2048),
                                  __ATOMIC_RELAXED, __HIP_MEMORY_SCOPE_AGENT);
      v[q][1] = __hip_atomic_load((const u64*)(src + q * 2048 + 2),
                                  __ATOMIC_RELAXED, __HIP_MEMORY_SCOPE_AGENT);
    }
  }
}
template <bool SC0>
static __device__ __forceinline__ void st_ex(u32* p, u32 v) {
  if constexpr (SC0)
    asm volatile("global_store_dword %0, %1, off sc0" ::"v"(p), "v"(v)
                 : "memory");
  else
    __hip_atomic_store(p, v, __ATOMIC_RELAXED, __HIP_MEMORY_SCOPE_AGENT);
}

// ---------------------------------------------------------------------------
// K0: split W_hh (fp32 [k=512][j=512]) into f16 hi + f16 lo*2^11, stored in
// MFMA B-fragment stream order (verified R3-R12).
// ---------------------------------------------------------------------------
__global__ void wsplit_kernel(const float* __restrict__ Whh,
                              _Float16* __restrict__ Whi,
                              _Float16* __restrict__ Wlo) {
  int gid = blockIdx.x * 256 + threadIdx.x;  // 0..32767
  int l = gid & 63, c = gid >> 6;            // c in [0,512)
  int kb = c & 15, jtg = c >> 4;
  int j = jtg * 16 + (l & 15);
  int k0 = kb * 32 + (l >> 4) * 8;
  _Float16 hi[8], lo[8];
#pragma unroll
  for (int e = 0; e < 8; ++e) {
    float v = Whh[(k0 + e) * HID + j];
    _Float16 h = (_Float16)v;
    hi[e] = h;
    lo[e] = (_Float16)((v - (float)h) * LOSCALE);
  }
  *(h8*)(Whi + (size_t)gid * 8) = *(const h8*)hi;
  *(h8*)(Wlo + (size_t)gid * 8) = *(const h8*)lo;
}

// ---------------------------------------------------------------------------
// K1: projE[v][j] = sum_d E[v][d] * W_xh[d][j] + b_xh[j]  (32000 x 512)
// ---------------------------------------------------------------------------
template <bool PF32>
__global__ __launch_bounds__(256) void proj_kernel(const float* __restrict__ E,
                                                   const float* __restrict__ Wxh,
                                                   const float* __restrict__ bxh,
                                                   void* __restrict__ projE) {
  __shared__ float El[32 * EMB];
  const int t = threadIdx.x;
  const int v0 = blockIdx.x * 32;
  {
    const float4* src = (const float4*)(E + (size_t)v0 * EMB);
    float4* dst = (float4*)El;
#pragma unroll
    for (int i = 0; i < 8; ++i) dst[t + i * 256] = src[t + i * 256];
  }
  __syncthreads();
  const int c0 = (t & 63) * 8;
  const int rg = t >> 6;
  float acc[8][8];
#pragma unroll
  for (int r = 0; r < 8; ++r)
#pragma unroll
    for (int c = 0; c < 8; ++c) acc[r][c] = 0.f;

#pragma unroll 4
  for (int d = 0; d < EMB; ++d) {
    float wv[8];
    *(float4*)&wv[0] = *(const float4*)&Wxh[d * HID + c0];
    *(float4*)&wv[4] = *(const float4*)&Wxh[d * HID + c0 + 4];
#pragma unroll
    for (int r = 0; r < 8; ++r) {
      float ev = El[(rg * 8 + r) * EMB + d];
#pragma unroll
      for (int c = 0; c < 8; ++c) acc[r][c] = fmaf(ev, wv[c], acc[r][c]);
    }
  }
  float bv[8];
  *(float4*)&bv[0] = *(const float4*)&bxh[c0];
  *(float4*)&bv[4] = *(const float4*)&bxh[c0 + 4];
#pragma unroll
  for (int r = 0; r < 8; ++r) {
    int row = v0 + rg * 8 + r;
    if (PF32) {
      float o[8];
#pragma unroll
      for (int c = 0; c < 8; ++c) o[c] = acc[r][c] + bv[c];
      *(float4*)((float*)projE + (size_t)row * HID + c0) = *(const float4*)&o[0];
      *(float4*)((float*)projE + (size_t)row * HID + c0 + 4) = *(const float4*)&o[4];
    } else {
      _Float16 o[8];
#pragma unroll
      for (int c = 0; c < 8; ++c) o[c] = (_Float16)(acc[r][c] + bv[c]);
      *(h8*)((_Float16*)projE + (size_t)row * HID + c0) = *(const h8*)o;
    }
  }
}

// ---------------------------------------------------------------------------
// K2: init. Buffer 0 = zeros (h0, epoch 0). Buffer 1 = per-u32 0x1 (invalid
// for t=1's expected epoch 0 — R12's verified fix). Claim region zeroed.
// ---------------------------------------------------------------------------
__global__ void init_kernel(float4* __restrict__ p) {
  int gid = blockIdx.x * 256 + threadIdx.x;
  if (gid < 16640) {
    float4 z = {0.f, 0.f, 0.f, 0.f};
    if (gid >= 8192 && gid < 16384) {
      float one = __uint_as_float(1u);
      z = (float4){one, one, one, one};
    }
    p[gid] = z;
  }
}

// ---------------------------------------------------------------------------
// Main recurrence loop — byte-identical math/protocol to the PASSING R12
// kernel (flagless epoch-bit sync), templated on exchange cache scope.
// ---------------------------------------------------------------------------
template <bool PF32, bool SC0>
static __device__ __forceinline__ void rnn_loop(
    const int* __restrict__ X, const _Float16* __restrict__ Whi,
    const _Float16* __restrict__ Wlo, const void* __restrict__ projE,
    const float* __restrict__ bhh, u32* __restrict__ hX,
    float* __restrict__ out, u32* hs, int tid, int grp, int cb) {
  const int w = tid >> 6, lane = tid & 63;
  const int g = lane >> 4, li = lane & 15;
  const int nb = grp * 16;
  const int jtg = cb * 8 + w;
  const int j = jtg * 16 + li;

  // --- W slice into registers, laundered so it stays resident ---
  h8 Wh[16], Wl[16];
  {
    const char* wb = (const char*)Whi + ((size_t)jtg * 16 * 64 + lane) * 16;
    const char* wb2 = (const char*)Wlo + ((size_t)jtg * 16 * 64 + lane) * 16;
#pragma unroll
    for (int kb = 0; kb < 16; ++kb) {
      Wh[kb] = *(const h8*)(wb + (size_t)kb * 1024);
      Wl[kb] = *(const h8*)(wb2 + (size_t)kb * 1024);
    }
#pragma unroll
    for (int kb = 0; kb < 16; ++kb) {
      f4v th = __builtin_bit_cast(f4v, Wh[kb]);
      f4v tl = __builtin_bit_cast(f4v, Wl[kb]);
      asm volatile("" : "+v"(th), "+v"(tl));
      Wh[kb] = __builtin_bit_cast(h8, th);
      Wl[kb] = __builtin_bit_cast(h8, tl);
    }
  }
  const float bias = bhh[j];

  const int hi2 = ((jtg & 1) << 1) | (li >> 3);
  const int pub0 = (li & 1) * 4096 + (jtg >> 1) * 256 + (hi2 << 6) + g * 16 +
                   ((li & 7) >> 1);
  u32* const hgrp = hX + grp * 8192;
  const bool oddli = (li & 1) != 0;

  const int* Xr[4];
#pragma unroll
  for (int i = 0; i < 4; ++i) Xr[i] = X + (size_t)(nb + g * 4 + i) * SEQ;

  for (int t = 0; t < SEQ; ++t) {
    float pv[4];
#pragma unroll
    for (int i = 0; i < 4; ++i) {
      int tok = Xr[i][t];
      if (PF32)
        pv[i] = ((const float*)projE)[(size_t)tok * HID + j];
      else
        pv[i] = (float)((const _Float16*)projE)[(size_t)tok * HID + j];
    }

    // validate+stage: reload 16 words until all carry the expected epoch bit
    const u32 e = (u32)(t >> 1) & 1u;
    const u32* src = hgrp + (t & 1) * 32768 + tid * 4;
    u64 v[4][2];
    {
      int tries = 0;
      while (true) {
        load8<SC0>(src, v);
        u64 orr = (v[0][0] | v[0][1]) | (v[1][0] | v[1][1]) |
                  (v[2][0] | v[2][1]) | (v[3][0] | v[3][1]);
        u64 andd = (v[0][0] & v[0][1]) & (v[1][0] & v[1][1]) &
                   (v[2][0] & v[2][1]) & (v[3][0] & v[3][1]);
        bool ok;
        if (e)
          ok = ((andd & 1ull) != 0) && (((andd >> 32) & 1ull) != 0);
        else
          ok = ((orr & 1ull) == 0) && (((orr >> 32) & 1ull) == 0);
        if (__all(ok) || ++tries > 200000) break;
      }
    }
#pragma unroll
    for (int q = 0; q < 4; ++q) {
      u32x4 d;
      d[0] = (u32)v[q][0]; d[1] = (u32)(v[q][0] >> 32);
      d[2] = (u32)v[q][1]; d[3] = (u32)(v[q][1] >> 32);
      *(u32x4*)(hs + tid * 4 + q * 2048) = d;
    }
    __syncthreads();

    // compute
    f4v a1 = {0.f, 0.f, 0.f, 0.f};
    f4v c1 = {0.f, 0.f, 0.f, 0.f};
    f4v c2 = {0.f, 0.f, 0.f, 0.f};
    const u32* hb_hi = hs + lane * 4;
    const u32* hb_lo = hb_hi + 4096;
#pragma unroll
    for (int kb = 0; kb < 16; ++kb) {
      h8 ahc = *(const h8*)(hb_hi + kb * 256);
      h8 alc = *(const h8*)(hb_lo + kb * 256);
      a1 = __builtin_amdgcn_mfma_f32_16x16x32_f16(ahc, Wh[kb], a1, 0, 0, 0);
      c1 = __builtin_amdgcn_mfma_f32_16x16x32_f16(ahc, Wl[kb], c1, 0, 0, 0);
      c2 = __builtin_amdgcn_mfma_f32_16x16x32_f16(alc, Wh[kb], c2, 0, 0, 0);
    }

    // epilogue: tanh; force epoch bit; pair lanes; publish
    u32* const hn = hgrp + ((t + 1) & 1) * 32768;
    const u32 ep = (u32)((t + 1) >> 1) & 1u;
    const bool lastt = (t == SEQ - 1);
#pragma unroll
    for (int i = 0; i < 4; ++i) {
      float vfull = a1[i] + INV_LOSCALE * (c1[i] + c2[i]) + bias + pv[i];
      float e2 = __expf(2.0f * vfull);
      float th = 1.0f - 2.0f / (e2 + 1.0f);
      _Float16 hh = (_Float16)th;
      u16 h16 = __builtin_bit_cast(u16, hh);
      if (!oddli) h16 = (u16)((h16 & 0xFFFEu) | ep);
      hh = __builtin_bit_cast(_Float16, h16);
      _Float16 hl = (_Float16)((th - (float)hh) * LOSCALE);
      u16 l16 = __builtin_bit_cast(u16, hl);
      if (!oddli) l16 = (u16)((l16 & 0xFFFEu) | ep);
      u32 pk = (u32)h16 | ((u32)l16 << 16);
      u32 nbv = (u32)__shfl_xor((int)pk, 1, 64);
      u32 word = oddli ? ((nbv >> 16) | (pk & 0xFFFF0000u))
                       : ((pk & 0xFFFFu) | (nbv << 16));
      st_ex<SC0>(hn + pub0 + i * 4, word);
      if (lastt) out[(nb + g * 4 + i) * HID + j] = th;
    }
    __syncthreads();
  }
}

// ---------------------------------------------------------------------------
// K3: claim XCD-colocated quads, handshake-verify sc0 connectivity, then run
// the R12 loop with sc0 (L2-served, ~4x cheaper RT) if verified, else sc1.
// Claim region (u32 words): xcdcnt[xcd]@xcd*32, groupcnt@256,
// quadgid@512+xcd*16+quad, hstest@640+grp*16+cb*4, verdict@768+grp*16+cb*4.
// ---------------------------------------------------------------------------
template <bool PF32>
__global__ __launch_bounds__(512, 2) void rnn_kernel(
    const int* __restrict__ X, const _Float16* __restrict__ Whi,
    const _Float16* __restrict__ Wlo, const void* __restrict__ projE,
    const float* __restrict__ bhh, u32* __restrict__ hX,
    u32* __restrict__ claim, float* __restrict__ out) {
  __shared__ u32 hs[8192];
  __shared__ int sh[3];
  const int tid = threadIdx.x;

  if (tid == 0) {
    u32 xcd;
    asm volatile("s_getreg_b32 %0, hwreg(HW_REG_XCC_ID)" : "=s"(xcd));
    xcd &= 7u;
    int mygrp = -1, mycb = 0;
    u32 slot = __hip_atomic_fetch_add(claim + xcd * 32, 1u, __ATOMIC_RELAXED,
                                      __HIP_MEMORY_SCOPE_AGENT);
    u32 quad = slot >> 2, pos = slot & 3;
    if (quad < 16u) {
      u32* qg = claim + 512 + xcd * 16 + quad;
      if (pos == 3) {
        u32 g = __hip_atomic_fetch_add(claim + 256, 1u, __ATOMIC_RELAXED,
                                       __HIP_MEMORY_SCOPE_AGENT);
        __hip_atomic_store(qg, (g < 4u) ? (g + 1u) : 255u, __ATOMIC_RELAXED,
                           __HIP_MEMORY_SCOPE_AGENT);
        if (g < 4u) mygrp = (int)g;
      } else {
        long grace = -1;
        for (u32 it = 0;; ++it) {
          u32 qv = __hip_atomic_load(qg, __ATOMIC_RELAXED,
                                     __HIP_MEMORY_SCOPE_AGENT);
          if (qv) {
            if (qv <= 4u) mygrp = (int)qv - 1;
            break;
          }
          u32 gc = __hip_atomic_load(claim + 256, __ATOMIC_RELAXED,
                                     __HIP_MEMORY_SCOPE_AGENT);
          if (gc >= 4u) {
            if (grace < 0) grace = (long)it + 30000;
            else if ((long)it > grace) break;
          }
          if (it > 200000u) break;  // hang guard
        }
      }
      mycb = (int)pos;
    }
    sh[0] = mygrp;
    sh[1] = mycb;
  }
  __syncthreads();
  const int grp = sh[0], cb = sh[1];
  if (grp < 0) return;  // surplus block

  // ---- sc0 connectivity handshake (one-time, verdict via reliable sc1) ----
  if (tid == 0) {
    u32* ht = claim + 640 + grp * 16;
    st_sc0_u32(ht + cb * 4, 1u);
    int seen = 0;
    for (u32 it = 0; it < 300u && seen < 4; ++it) {
      seen = 0;
#pragma unroll
      for (int b = 0; b < 4; ++b) seen += (ld_sc0_u32(ht + b * 4) == 1u);
    }
    u32* vd = claim + 768 + grp * 16;
    __hip_atomic_store(vd + cb * 4, (seen == 4) ? 2u : 1u, __ATOMIC_RELAXED,
                       __HIP_MEMORY_SCOPE_AGENT);
    u32 all = 2u;
#pragma unroll
    for (int b = 0; b < 4; ++b) {
      u32 vv = 0;
      for (u32 it = 0; it < 10000u; ++it) {
        vv = __hip_atomic_load(vd + b * 4, __ATOMIC_RELAXED,
                               __HIP_MEMORY_SCOPE_AGENT);
        if (vv) break;
      }
      if (vv != 2u) all = 1u;
    }
    sh[2] = (all == 2u) ? 1 : 0;
  }
  __syncthreads();
  const bool usesc0 = sh[2] != 0;

  if (usesc0)
    rnn_loop<PF32, true>(X, Whi, Wlo, projE, bhh, hX, out, hs, tid, grp, cb);
  else
    rnn_loop<PF32, false>(X, Whi, Wlo, projE, bhh, hX, out, hs, tid, grp, cb);
}

// ---------------------------------------------------------------------------
extern "C" void kernel_launch(void* const* d_in, const int* in_sizes, int n_in,
                              void* d_out, int out_size, void* d_ws,
                              size_t ws_size, hipStream_t stream) {
  const int* X = (const int*)d_in[0];
  const float* E = (const float*)d_in[1];
  const float* Whh = (const float*)d_in[2];
  const float* bhh = (const float*)d_in[3];
  const float* Wxh = (const float*)d_in[4];
  const float* bxh = (const float*)d_in[5];
  float* out = (float*)d_out;

  char* ws = (char*)d_ws;
  _Float16* Whi = (_Float16*)(ws + WS_WHI);
  _Float16* Wlo = (_Float16*)(ws + WS_WLO);
  u32* hX = (u32*)(ws + WS_HG);
  u32* claim = (u32*)(ws + WS_CLAIM);
  void* projE = (void*)(ws + WS_PROJ);
  const bool pf32 = ws_size >= (size_t)WS_PROJ + (size_t)NV * HID * sizeof(float);

  wsplit_kernel<<<128, 256, 0, stream>>>(Whh, Whi, Wlo);
  init_kernel<<<65, 256, 0, stream>>>((float4*)(ws + WS_HG));
  if (pf32) {
    proj_kernel<true><<<NV / 32, 256, 0, stream>>>(E, Wxh, bxh, projE);
    rnn_kernel<true><<<64, 512, 0, stream>>>(X, Whi, Wlo, projE, bhh, hX,
                                             claim, out);
  } else {
    proj_kernel<false><<<NV / 32, 256, 0, stream>>>(E, Wxh, bxh, projE);
    rnn_kernel<false><<<64, 512, 0, stream>>>(X, Whi, Wlo, projE, bhh, hX,
                                              claim, out);
  }
}